// Round 8
// baseline (285.907 us; speedup 1.0000x reference)
//
#include <hip/hip_runtime.h>
#include <hip/hip_bf16.h>

// Problem constants (match reference)
#define NPTS 400000          // == 6250 * 64 exactly
#define NVOX 100000
#define EPSB 1e-3f
#define NTILE 6250
#define NBLK_SCAN 391        // ceil(NVOX/256)
#define GBLK 782             // k_prep grid (2-3 pts/thread)

// ws layout (in floats) — ~108 MB
#define OFF_ACC4   0                          // 4*NVOX [cnt,sx,sy,sz]
#define OFF_ACCI   (4*NVOX)                   // NVOX per-voxel intensity sums
#define OFF_AMOM   (5*NVOX)                   // 32 slots * 16 point moments
#define OFF_BMOM   (OFF_AMOM + 512)           // 32 slots * 32 voxel moments
#define OFF_P1     (OFF_BMOM + 1024)          // 32 slots * 128
#define ZERO_FLOATS (OFF_P1 + 4096)           // zeroed prefix (~2.0 MB)
#define OFF_STATS  ZERO_FLOATS                // 128 (sc0|bi0, written by k_gasm)
#define OFF_V0     (OFF_STATS + 128)          // NVOX*64 fp32 h0 max (spanning rows zeroed by scan3)
#define OFF_Y1M    (OFF_V0 + NVOX*64)         // NVOX*64 raw y1 max (fkey; spanning rows zeroed)
#define OFF_VTMP   (OFF_Y1M + NVOX*64)        // NVOX
#define OFF_BSUM   (OFF_VTMP + NVOX)          // 512
#define OFF_VOFF   (OFF_BSUM + 512)           // NVOX (scatter cursors)
#define OFF_VSTART (OFF_VOFF + NVOX)          // NVOX+8 (+ sentinel)
#define OFF_ORD    (OFF_VSTART + NVOX + 8)    // NPTS
#define OFF_VS     (OFF_ORD + NPTS)           // NPTS (vsorted, sequential fill by scan3)
#define OFF_W0F    (OFF_VS + NPTS)            // 640
#define OFF_W1B    (OFF_W0F + 640)            // 4096 floats = 8192 bf16
#define OFF_H0T    (OFF_W1B + 4096)           // NPTS*64 bf16 (sorted h0 tiles)

#define XTB_LD 136
#define HT_LD  65

typedef __bf16 bf16x8 __attribute__((ext_vector_type(8)));
typedef float  f32x4  __attribute__((ext_vector_type(4)));

__device__ __forceinline__ float b2f(__hip_bfloat16 h) { return __bfloat162float(h); }
__device__ __forceinline__ float bfbits2f(unsigned short u) {
    return __uint_as_float((unsigned int)u << 16);
}
__device__ __forceinline__ unsigned short bf16u(float f) {
    __hip_bfloat16 h = __float2bfloat16(f);
    return __builtin_bit_cast(unsigned short, h);
}
__device__ __forceinline__ unsigned int fkey(float f) {
    unsigned int u = __float_as_uint(f);
    return (u & 0x80000000u) ? ~u : (u | 0x80000000u);
}
__device__ __forceinline__ float funkey(unsigned int k) {
    unsigned int u = (k & 0x80000000u) ? (k & 0x7FFFFFFFu) : ~k;
    return __uint_as_float(u);
}

__device__ __forceinline__ void compute_x(const __hip_bfloat16* __restrict__ feat,
                                          const float* __restrict__ acc4,
                                          const int* __restrict__ coors,
                                          long i, int v, float* xv) {
    ushort4 f4 = *(const ushort4*)(feat + 4 * i);
    float px = bfbits2f(f4.x), py = bfbits2f(f4.y), pz = bfbits2f(f4.z), it = bfbits2f(f4.w);
    float4 a4 = *(const float4*)&acc4[4 * (long)v];
    float ic = 1.0f / a4.x;
    int4 c4 = *(const int4*)&coors[4 * (long)v];   // (b, z, y, x)
    xv[0] = px; xv[1] = py; xv[2] = pz;
    xv[3] = px - a4.y * ic; xv[4] = py - a4.z * ic; xv[5] = pz - a4.w * ic;
    xv[6] = px - ((float)c4.w * 0.2f + 0.1f);
    xv[7] = py - ((float)c4.z * 0.2f + 0.1f - 40.0f);
    xv[8] = pz - ((float)c4.y * 4.0f + 2.0f - 3.0f);
    xv[9] = it;
}

// ---- K1: per-voxel count + xyz sums + intensity sums; last block converts
// weights (W0 -> fp32; W1 -> bf16 MFMA B-fragment order). ----
__global__ void k_vsum(const __hip_bfloat16* __restrict__ feat,
                       const int* __restrict__ inv,
                       float* __restrict__ acc4, float* __restrict__ accI,
                       const __hip_bfloat16* __restrict__ W0,
                       const __hip_bfloat16* __restrict__ W1,
                       float* __restrict__ W0f, unsigned short* __restrict__ w1b) {
    if (blockIdx.x == 6250) {
        int t = threadIdx.x;
        for (int j = t; j < 640; j += 256) W0f[j] = b2f(W0[j]);
        for (int f = t; f < 8192; f += 256) {
            int j  = f & 7;
            int l  = (f >> 3) & 63;
            int ks = (f >> 9) & 3;
            int ct = f >> 11;
            int ch = ct * 16 + (l & 15);
            int k  = ks * 32 + ((l >> 4) & 3) * 8 + j;
            w1b[f] = __builtin_bit_cast(unsigned short, W1[ch * 128 + k]);
        }
        return;
    }
    long t = (long)blockIdx.x * 256 + threadIdx.x;
    int pt = (int)(t >> 2);
    int comp = (int)(t & 3);
    int v = inv[pt];
    if (comp == 0) {
        atomicAdd(&acc4[(long)v * 4], 1.0f);
        atomicAdd(&accI[v], b2f(feat[4 * pt + 3]));
    } else {
        atomicAdd(&acc4[(long)v * 4 + comp], b2f(feat[4 * pt + comp - 1]));
    }
}

// ---- prefix scan of voxel counts ----
__global__ void k_scan1(const float* __restrict__ acc4,
                        int* __restrict__ vtmp, int* __restrict__ bsum) {
    __shared__ int sc[256];
    int b = blockIdx.x, t = threadIdx.x;
    int v = b * 256 + t;
    int c = (v < NVOX) ? (int)acc4[4 * (long)v] : 0;
    sc[t] = c;
    __syncthreads();
    int val = c;
    for (int off = 1; off < 256; off <<= 1) {
        int x = (t >= off) ? sc[t - off] : 0;
        __syncthreads();
        val += x; sc[t] = val;
        __syncthreads();
    }
    if (v < NVOX) vtmp[v] = val - c;
    if (t == 255) bsum[b] = val;
}

__global__ void k_scan2(int* __restrict__ bsum) {
    __shared__ int sc[512];
    int t = threadIdx.x;
    int c = (t < NBLK_SCAN) ? bsum[t] : 0;
    sc[t] = c;
    __syncthreads();
    int val = c;
    for (int off = 1; off < 512; off <<= 1) {
        int x = (t >= off) ? sc[t - off] : 0;
        __syncthreads();
        val += x; sc[t] = val;
        __syncthreads();
    }
    if (t < NBLK_SCAN) bsum[t] = val - c;
}

// ---- scan3: finalize offsets; fill vsorted by sequential per-voxel runs;
// zero-init v0/y1m rows ONLY for window-spanning voxels. ----
__global__ void k_scan3(const int* __restrict__ vtmp, const int* __restrict__ bsum,
                        int* __restrict__ voff, int* __restrict__ vstart,
                        int* __restrict__ vsorted,
                        float* __restrict__ v0, unsigned int* __restrict__ y1m) {
    int v = blockIdx.x * 256 + threadIdx.x;
    if (v < NVOX) {
        int s0 = vtmp[v] + bsum[v >> 8];
        voff[v] = s0;
        vstart[v] = s0;
        int s1;
        if (v + 1 < NVOX) s1 = vtmp[v + 1] + bsum[(v + 1) >> 8];
        else              s1 = NPTS;
        for (int j = s0; j < s1; j++) vsorted[j] = v;
        if ((s0 >> 4) != ((s1 - 1) >> 4)) {   // spans a window boundary
            float4 z4 = {0.f, 0.f, 0.f, 0.f};
            float4* pv = (float4*)&v0[(long)v * 64];
            float4* py = (float4*)&y1m[(long)v * 64];
#pragma unroll
            for (int u = 0; u < 16; u++) { pv[u] = z4; py[u] = z4; }
        }
    }
    if (v == 0) vstart[NVOX] = NPTS;
}

// ---- K2: counting-sort scatter (ord only) + GLOBAL point moments A[14]
// (streaming feat; no acc4/coors gathers — the Gram is assembled from
// moments by k_gasm). Slotted atomic tail (32 slots, no contention). ----
__global__ __launch_bounds__(256, 4)
void k_prep(const __hip_bfloat16* __restrict__ feat,
            const int* __restrict__ inv,
            int* __restrict__ voff,
            int* __restrict__ ord,
            float* __restrict__ amom) {
    __shared__ float gs[16];
    int t = threadIdx.x;
    if (t < 16) gs[t] = 0.0f;
    __syncthreads();

    float a[14];
#pragma unroll
    for (int k = 0; k < 14; k++) a[k] = 0.0f;

    for (long i = (long)blockIdx.x * 256 + t; i < NPTS; i += (long)GBLK * 256) {
        ushort4 f4 = *(const ushort4*)(feat + 4 * i);
        float px = bfbits2f(f4.x), py = bfbits2f(f4.y);
        float pz = bfbits2f(f4.z), it = bfbits2f(f4.w);
        a[0] += px;      a[1] += py;      a[2] += pz;
        a[3] += px * px; a[4] += py * px; a[5] += py * py;
        a[6] += pz * px; a[7] += pz * py; a[8] += pz * pz;
        a[9] += it;      a[10] += it * px; a[11] += it * py; a[12] += it * pz;
        a[13] += it * it;
        int v = inv[i];
        int pos = atomicAdd(&voff[v], 1);
        ord[pos] = (int)i;
    }

#pragma unroll
    for (int k = 0; k < 14; k++) {
        float s = a[k];
        for (int m = 32; m >= 1; m >>= 1) s += __shfl_xor(s, m);
        if ((t & 63) == 0) atomicAdd(&gs[k], s);
    }
    __syncthreads();
    if (t < 14) atomicAdd(&amom[(blockIdx.x & 31) * 16 + t], gs[t]);
}

// ---- K2b: VOXEL moments B[30] (streaming over acc4/accI/coors). ----
__global__ void k_bmom(const float* __restrict__ acc4,
                       const float* __restrict__ accI,
                       const int* __restrict__ coors,
                       float* __restrict__ bmom) {
    __shared__ float gs[32];
    int t = threadIdx.x;
    if (t < 32) gs[t] = 0.0f;
    __syncthreads();

    int v = blockIdx.x * 256 + t;
    float n = 0, sx = 0, sy = 0, sz = 0, I = 0, cx = 0, cy = 0, cz = 0, in = 0;
    if (v < NVOX) {
        float4 a4 = *(const float4*)&acc4[4 * (long)v];
        n = a4.x; sx = a4.y; sy = a4.z; sz = a4.w;
        I = accI[v];
        int4 c4 = *(const int4*)&coors[4 * (long)v];   // (b, z, y, x)
        cx = (float)c4.w * 0.2f + 0.1f;
        cy = (float)c4.z * 0.2f + 0.1f - 40.0f;
        cz = (float)c4.y * 4.0f + 2.0f - 3.0f;
        in = 1.0f / n;
    }
    float vals[30];
    // B1 = s s^T / n (lower-tri)
    vals[0] = sx * sx * in; vals[1] = sy * sx * in; vals[2] = sy * sy * in;
    vals[3] = sz * sx * in; vals[4] = sz * sy * in; vals[5] = sz * sz * in;
    // B2[a][b] = s_a c_b
    vals[6]  = sx * cx; vals[7]  = sx * cy; vals[8]  = sx * cz;
    vals[9]  = sy * cx; vals[10] = sy * cy; vals[11] = sy * cz;
    vals[12] = sz * cx; vals[13] = sz * cy; vals[14] = sz * cz;
    // B3 = n c c^T (lower-tri)
    vals[15] = n * cx * cx; vals[16] = n * cy * cx; vals[17] = n * cy * cy;
    vals[18] = n * cz * cx; vals[19] = n * cz * cy; vals[20] = n * cz * cz;
    // B5 = n c
    vals[21] = n * cx; vals[22] = n * cy; vals[23] = n * cz;
    // B6 = I s / n
    vals[24] = I * sx * in; vals[25] = I * sy * in; vals[26] = I * sz * in;
    // B7 = I c
    vals[27] = I * cx; vals[28] = I * cy; vals[29] = I * cz;

#pragma unroll
    for (int k = 0; k < 30; k++) {
        float s = vals[k];
        for (int m = 32; m >= 1; m >>= 1) s += __shfl_xor(s, m);
        if ((t & 63) == 0) atomicAdd(&gs[k], s);
    }
    __syncthreads();
    if (t < 30) atomicAdd(&bmom[(blockIdx.x & 31) * 32 + t], gs[t]);
}

// ---- K2c: assemble Gram from moments, finalize BN0 scale/bias ONCE. ----
__global__ void k_gasm(const float* __restrict__ amom, const float* __restrict__ bmom,
                       const float* __restrict__ W0f,
                       const __hip_bfloat16* __restrict__ g0,
                       const __hip_bfloat16* __restrict__ be0,
                       float* __restrict__ stats) {
    __shared__ float A[16], B[32], g[72];
    int t = threadIdx.x;
    if (t < 16) {
        float s = 0.0f;
        for (int sl = 0; sl < 32; sl++) s += amom[sl * 16 + t];
        A[t] = s;
    } else if (t < 48) {
        int k = t - 16;
        float s = 0.0f;
        for (int sl = 0; sl < 32; sl++) s += bmom[sl * 32 + k];
        B[k] = s;
    }
    __syncthreads();

    if (t == 0) {
        auto A2f = [&](int p, int q) { int h = p > q ? p : q, l = p > q ? q : p;
                                       return A[3 + h * (h + 1) / 2 + l]; };
        auto B1f = [&](int p, int q) { int h = p > q ? p : q, l = p > q ? q : p;
                                       return B[h * (h + 1) / 2 + l]; };
        auto B2f = [&](int p, int q) { return B[6 + p * 3 + q]; };   // Σ p_p c_q
        auto B3f = [&](int p, int q) { int h = p > q ? p : q, l = p > q ? q : p;
                                       return B[15 + h * (h + 1) / 2 + l]; };
        // S sums
        g[0] = A[0]; g[1] = A[1]; g[2] = A[2];
        g[3] = 0.0f; g[4] = 0.0f; g[5] = 0.0f;
        g[6] = A[0] - B[21]; g[7] = A[1] - B[22]; g[8] = A[2] - B[23];
        g[9] = A[9];
        // Gram (lower-tri)
        for (int hi = 0; hi < 10; hi++) {
            for (int lo = 0; lo <= hi; lo++) {
                int ch = hi < 3 ? 0 : (hi < 6 ? 1 : (hi < 9 ? 2 : 3));
                int cl = lo < 3 ? 0 : (lo < 6 ? 1 : (lo < 9 ? 2 : 3));
                int ah = hi - (ch == 1 ? 3 : (ch == 2 ? 6 : 0));
                int al = lo - (cl == 1 ? 3 : (cl == 2 ? 6 : 0));
                float val;
                if (ch == 3 && cl == 3)      val = A[13];
                else if (ch == 3) {
                    if (cl == 0)             val = A[10 + al];
                    else if (cl == 1)        val = A[10 + al] - B[24 + al];
                    else                     val = A[10 + al] - B[27 + al];
                }
                else if (ch == 2 && cl == 2) val = A2f(ah, al) - B2f(ah, al) - B2f(al, ah) + B3f(ah, al);
                else if (ch == 2 && cl == 0) val = A2f(ah, al) - B2f(al, ah);
                else if (ch == 0)            val = A2f(ah, al);        // cl==0
                else                         val = A2f(ah, al) - B1f(ah, al);  // (M,*) and (C,M)
                g[10 + hi * (hi + 1) / 2 + lo] = val;
            }
        }
    }
    __syncthreads();

    if (t < 64) {
        int c = t;
        float wr[10];
#pragma unroll
        for (int k = 0; k < 10; k++) wr[k] = W0f[c * 10 + k];
        float sum = 0.0f, sq = 0.0f;
#pragma unroll
        for (int a = 0; a < 10; a++) {
            sum += wr[a] * g[a];
            float ta = 0.0f;
#pragma unroll
            for (int b = 0; b < 10; b++) {
                int hi = (a >= b) ? a : b, lo = (a >= b) ? b : a;
                ta += wr[b] * g[10 + hi * (hi + 1) / 2 + lo];
            }
            sq += wr[a] * ta;
        }
        float mu  = sum * (1.0f / NPTS);
        float var = sq * (1.0f / NPTS) - mu * mu;
        float gg  = b2f(g0[c]) * rsqrtf(var + EPSB);
        stats[c]      = gg;
        stats[64 + c] = b2f(be0[c]) - mu * gg;
    }
}

// ---- K3: h0 = relu(bn0(y0)); sorted tile. Stats are precomputed (k_gasm).
// Window-complete voxels get PLAIN coalesced stores; only window-spanning
// voxels use atomicMax. Spills the h0 tile (bf16, sorted layout). ----
__global__ __launch_bounds__(256, 6)
void k_h0max(const int* __restrict__ ord, const int* __restrict__ vsorted,
             const int* __restrict__ vstart,
             const __hip_bfloat16* __restrict__ feat,
             const float* __restrict__ acc4, const int* __restrict__ coors,
             const float* __restrict__ W0f, const float* __restrict__ stats,
             float* __restrict__ v0, unsigned short* __restrict__ h0t) {
    __shared__ float ht[64 * HT_LD];      // 16640 B
    __shared__ int invs[64];
    __shared__ float sc0s[64], bi0s[64];
    int t = threadIdx.x, w = t >> 6, l = t & 63;
    int base = blockIdx.x * 64;
    int i = ord[base + l];
    int v = vsorted[base + l];
    if (w == 0) { invs[l] = v; sc0s[l] = stats[l]; }
    else if (w == 1) bi0s[l] = stats[64 + l];

    float xv[10];
    compute_x(feat, acc4, coors, (long)i, v, xv);
    __syncthreads();

    int cw = w * 16;
#pragma unroll
    for (int j = 0; j < 16; j++) {
        int c = cw + j;
        float y = 0.0f;
#pragma unroll
        for (int k = 0; k < 10; k++) y += xv[k] * W0f[c*10 + k];
        ht[l * HT_LD + c] = fmaxf(sc0s[c] * y + bi0s[c], 0.0f);
    }
    __syncthreads();

    // spill h0 tile (bf16, sorted layout)
#pragma unroll
    for (int u = 0; u < 2; u++) {
        int idx = t + u * 256;          // 0..511, coalesced uint4 per thread
        int pt2 = idx >> 3;
        int c0 = (idx & 7) * 8;
        const float* src = &ht[pt2 * HT_LD + c0];
        float4 a  = *(const float4*)src;
        float4 b4 = *(const float4*)(src + 4);
        uint4 o;
        o.x = (unsigned int)bf16u(a.x)  | ((unsigned int)bf16u(a.y)  << 16);
        o.y = (unsigned int)bf16u(a.z)  | ((unsigned int)bf16u(a.w)  << 16);
        o.z = (unsigned int)bf16u(b4.x) | ((unsigned int)bf16u(b4.y) << 16);
        o.w = (unsigned int)bf16u(b4.z) | ((unsigned int)bf16u(b4.w) << 16);
        *(uint4*)&h0t[(long)(base + pt2) * 64 + c0] = o;
    }

    // lane = channel; wave walks its 16 sorted points; run-combine
    unsigned int mk = 0u;
#pragma unroll
    for (int j = 0; j < 16; j++) {
        int p = cw + j;
        unsigned int hb = __float_as_uint(ht[p * HT_LD + l]);
        mk = (hb > mk) ? hb : mk;
        if (j == 15 || invs[p + 1] != invs[p]) {
            int vv = invs[p];
            int s0 = vstart[vv], s1 = vstart[vv + 1];
            unsigned int* dst = (unsigned int*)&v0[(long)vv * 64 + l];
            if (s0 >= base + cw && s1 <= base + cw + 16)
                *dst = mk;                 // voxel complete in window: final value
            else
                atomicMax(dst, mk);        // spans window/tile boundary
            mk = 0u;
        }
    }
}

// ---- K4: layer-1 MFMA over sorted tiles (unchanged). ----
__global__ __launch_bounds__(256, 6)
void k_mfma_stats(const int* __restrict__ vsorted,
                  const int* __restrict__ vstart,
                  const unsigned short* __restrict__ h0t,
                  const unsigned short* __restrict__ w1b,
                  const float* __restrict__ v0,
                  float* __restrict__ P1,
                  unsigned int* __restrict__ y1m) {
    __shared__ union {
        unsigned short xtb[64 * XTB_LD];
        float ht[64 * HT_LD];
    } sm;
    __shared__ int invs[64];
    int t = threadIdx.x, w = t >> 6, l = t & 63;
    int quad = l >> 4, lm = l & 15;
    int base = blockIdx.x * 64;
    if (w == 0) invs[l] = vsorted[base + l];

    bf16x8 bfrag[4];
    const uint4* wf = (const uint4*)w1b;
#pragma unroll
    for (int ks = 0; ks < 4; ks++)
        bfrag[ks] = __builtin_bit_cast(bf16x8, wf[(w * 4 + ks) * 64 + l]);

#pragma unroll
    for (int u = 0; u < 2; u++) {
        int idx = t + u * 256;
        int pt = idx >> 3, c0 = (idx & 7) * 8;
        uint4 d = *(const uint4*)&h0t[(long)(base + pt) * 64 + c0];
        *(uint4*)&sm.xtb[pt * XTB_LD + c0] = d;
    }
    {
        int p = t >> 2, q = t & 3;
        int vv = vsorted[base + p];
        const float4* src = (const float4*)&v0[(long)vv * 64 + q * 16];
#pragma unroll
        for (int u = 0; u < 4; u++) {
            float4 f4 = src[u];
            ushort4 s4 = { bf16u(f4.x), bf16u(f4.y), bf16u(f4.z), bf16u(f4.w) };
            *(ushort4*)&sm.xtb[p * XTB_LD + 64 + q * 16 + 4 * u] = s4;
        }
    }
    __syncthreads();

    f32x4 acc[4];
#pragma unroll
    for (int pg = 0; pg < 4; pg++) acc[pg] = (f32x4){0.f, 0.f, 0.f, 0.f};
#pragma unroll
    for (int ks = 0; ks < 4; ks++) {
#pragma unroll
        for (int pg = 0; pg < 4; pg++) {
            const uint4* ap = (const uint4*)&sm.xtb[(pg * 16 + lm) * XTB_LD + ks * 32 + quad * 8];
            bf16x8 a = __builtin_bit_cast(bf16x8, *ap);
            acc[pg] = __builtin_amdgcn_mfma_f32_16x16x32_bf16(a, bfrag[ks], acc[pg], 0, 0, 0);
        }
    }

    float ssum = 0.0f, ssq = 0.0f;
#pragma unroll
    for (int pg = 0; pg < 4; pg++) {
#pragma unroll
        for (int r = 0; r < 4; r++) {
            float y = acc[pg][r];
            ssum += y; ssq += y * y;
        }
    }
    __syncthreads();

#pragma unroll
    for (int pg = 0; pg < 4; pg++) {
#pragma unroll
        for (int r = 0; r < 4; r++)
            sm.ht[(pg * 16 + quad * 4 + r) * HT_LD + w * 16 + lm] = acc[pg][r];
    }
    __syncthreads();

    unsigned int mk = 0u;
    int cw = w * 16;
#pragma unroll
    for (int j = 0; j < 16; j++) {
        int p = cw + j;
        unsigned int k2 = fkey(sm.ht[p * HT_LD + l]);
        mk = (k2 > mk) ? k2 : mk;
        if (j == 15 || invs[p + 1] != invs[p]) {
            int vv = invs[p];
            int s0 = vstart[vv], s1 = vstart[vv + 1];
            unsigned int* dst = &y1m[(long)vv * 64 + l];
            if (s0 >= base + cw && s1 <= base + cw + 16)
                *dst = mk;
            else
                atomicMax(dst, mk);
            mk = 0u;
        }
    }

    ssum += __shfl_xor(ssum, 16); ssq += __shfl_xor(ssq, 16);
    ssum += __shfl_xor(ssum, 32); ssq += __shfl_xor(ssq, 32);
    if (l < 16) {
        int slot = blockIdx.x & 31;
        atomicAdd(&P1[slot * 128 + w * 16 + lm], ssum);
        atomicAdd(&P1[slot * 128 + 64 + w * 16 + lm], ssq);
    }
}

// ---- K5: emit output with INLINE BN1 finalize (unchanged). ----
#define OUTBLK 512
__global__ __launch_bounds__(256)
void k_out(const unsigned int* __restrict__ y1m,
           const float* __restrict__ P1,
           const __hip_bfloat16* __restrict__ gamma,
           const __hip_bfloat16* __restrict__ beta,
           const int* __restrict__ coors,
           float* __restrict__ out) {
    __shared__ float sc1s[64], bi1s[64];
    int t = threadIdx.x;
    if (t < 64) {
        float sum = 0.0f, sq = 0.0f;
        for (int s = 0; s < 32; s++) {
            sum += P1[s*128 + t];
            sq  += P1[s*128 + 64 + t];
        }
        float mu  = sum * (1.0f / NPTS);
        float var = sq * (1.0f / NPTS) - mu * mu;
        float g   = b2f(gamma[t]) * rsqrtf(var + EPSB);
        sc1s[t] = g;
        bi1s[t] = b2f(beta[t]) - mu * g;
    }
    __syncthreads();

    const long n4feat = (long)NVOX * 16;
    const long n4all  = n4feat + NVOX;
    const long nfeat  = (long)NVOX * 64;
    for (long idx = (long)blockIdx.x * 256 + t; idx < n4all; idx += (long)OUTBLK * 256) {
        if (idx < n4feat) {
            uint4 kk = ((const uint4*)y1m)[idx];
            int c0 = (int)((idx * 4) & 63);
            float4 o;
            o.x = fmaxf(sc1s[c0+0] * funkey(kk.x) + bi1s[c0+0], 0.0f);
            o.y = fmaxf(sc1s[c0+1] * funkey(kk.y) + bi1s[c0+1], 0.0f);
            o.z = fmaxf(sc1s[c0+2] * funkey(kk.z) + bi1s[c0+2], 0.0f);
            o.w = fmaxf(sc1s[c0+3] * funkey(kk.w) + bi1s[c0+3], 0.0f);
            ((float4*)out)[idx] = o;
        } else {
            long vi = idx - n4feat;
            int4 c4 = ((const int4*)coors)[vi];
            float4 o;
            o.x = b2f(__float2bfloat16((float)c4.x));
            o.y = b2f(__float2bfloat16((float)c4.y));
            o.z = b2f(__float2bfloat16((float)c4.z));
            o.w = b2f(__float2bfloat16((float)c4.w));
            ((float4*)(out + nfeat))[vi] = o;
        }
    }
}

extern "C" void kernel_launch(void* const* d_in, const int* in_sizes, int n_in,
                              void* d_out, int out_size, void* d_ws, size_t ws_size,
                              hipStream_t stream) {
    const __hip_bfloat16* feat = (const __hip_bfloat16*)d_in[0];
    const __hip_bfloat16* W0   = (const __hip_bfloat16*)d_in[1];
    const __hip_bfloat16* g0   = (const __hip_bfloat16*)d_in[2];
    const __hip_bfloat16* be0  = (const __hip_bfloat16*)d_in[3];
    const __hip_bfloat16* W1   = (const __hip_bfloat16*)d_in[4];
    const __hip_bfloat16* g1   = (const __hip_bfloat16*)d_in[5];
    const __hip_bfloat16* be1  = (const __hip_bfloat16*)d_in[6];
    const int* inv   = (const int*)d_in[7];
    const int* coors = (const int*)d_in[8];
    float* out = (float*)d_out;

    float* ws    = (float*)d_ws;
    float* acc4  = ws + OFF_ACC4;
    float* accI  = ws + OFF_ACCI;
    float* amom  = ws + OFF_AMOM;
    float* bmom  = ws + OFF_BMOM;
    float* P1    = ws + OFF_P1;
    float* stats = ws + OFF_STATS;
    float* v0    = ws + OFF_V0;
    unsigned int* y1m = (unsigned int*)(ws + OFF_Y1M);
    int* vtmp    = (int*)(ws + OFF_VTMP);
    int* bsum    = (int*)(ws + OFF_BSUM);
    int* voff    = (int*)(ws + OFF_VOFF);
    int* vstart  = (int*)(ws + OFF_VSTART);
    int* ord     = (int*)(ws + OFF_ORD);
    int* vsorted = (int*)(ws + OFF_VS);
    float* W0f   = ws + OFF_W0F;
    unsigned short* w1b = (unsigned short*)(ws + OFF_W1B);
    unsigned short* h0t = (unsigned short*)(ws + OFF_H0T);

    // Zero only atomic-accumulated buffers (acc4, accI, amom, bmom, P1).
    hipMemsetAsync(ws, 0, (size_t)ZERO_FLOATS * sizeof(float), stream);

    k_vsum<<<6251, 256, 0, stream>>>(feat, inv, acc4, accI, W0, W1, W0f, w1b);
    k_scan1<<<NBLK_SCAN, 256, 0, stream>>>(acc4, vtmp, bsum);
    k_scan2<<<1, 512, 0, stream>>>(bsum);
    k_scan3<<<NBLK_SCAN, 256, 0, stream>>>(vtmp, bsum, voff, vstart, vsorted, v0, y1m);
    k_bmom<<<NBLK_SCAN, 256, 0, stream>>>(acc4, accI, coors, bmom);
    k_prep<<<GBLK, 256, 0, stream>>>(feat, inv, voff, ord, amom);
    k_gasm<<<1, 128, 0, stream>>>(amom, bmom, W0f, g0, be0, stats);
    k_h0max<<<NTILE, 256, 0, stream>>>(ord, vsorted, vstart, feat, acc4, coors,
                                       W0f, stats, v0, h0t);
    k_mfma_stats<<<NTILE, 256, 0, stream>>>(vsorted, vstart, h0t, w1b, v0, P1, y1m);
    k_out<<<OUTBLK, 256, 0, stream>>>(y1m, P1, g1, be1, coors, out);
}